// Round 5
// baseline (570.828 us; speedup 1.0000x reference)
//
#include <hip/hip_runtime.h>
#include <math.h>

#define NTOT 10790
#define NTOT2 5395
#define EPSF 1e-6f

__device__ __forceinline__ float block_reduce_sum(float v, float* red) {
    int tid = threadIdx.x;
    red[tid] = v; __syncthreads();
    for (int off = 128; off > 0; off >>= 1) {
        if (tid < off) red[tid] += red[tid + off];
        __syncthreads();
    }
    float r = red[0];
    __syncthreads();
    return r;
}

// strict total order: score desc, idx asc (idx unique -> never equal)
__device__ __forceinline__ bool kvGreater(float as, int ai, float bs, int bi) {
    return (as > bs) || (as == bs && ai < bi);
}

// bitonic sort of 64 lanes' (s,i), descending, register-only
__device__ __forceinline__ void sort64(float& s, int& i, int lane) {
    #pragma unroll
    for (int k = 2; k <= 64; k <<= 1) {
        #pragma unroll
        for (int j = k >> 1; j > 0; j >>= 1) {
            float os = __shfl_xor(s, j, 64);
            int   oi = __shfl_xor(i, j, 64);
            bool lower = (lane & j) == 0;
            bool blockDesc = (lane & k) == 0;
            bool keepG = (blockDesc == lower);
            bool og = kvGreater(os, oi, s, i);
            if (og == keepG) { s = os; i = oi; }
        }
    }
}

// merge two descending sorted-64 lists (a, b) -> a = descending top-64 of union
__device__ __forceinline__ void merge64(float& as, int& ai, float bs, int bi, int lane) {
    float rbs = __shfl(bs, 63 - lane, 64);
    int   rbi = __shfl(bi, 63 - lane, 64);
    if (!kvGreater(as, ai, rbs, rbi)) { as = rbs; ai = rbi; }
    #pragma unroll
    for (int j = 32; j > 0; j >>= 1) {
        float os = __shfl_xor(as, j, 64);
        int   oi = __shfl_xor(ai, j, 64);
        bool lower = (lane & j) == 0;
        bool og = kvGreater(os, oi, as, ai);
        if (og == lower) { as = os; ai = oi; }
    }
}

// grid (256 ch, 8 batch, 3 levels), block 256.
// Computes resized mask inline; c==0 blocks write wsm+msum; last block per
// (b,level) (device-scope atomic elect) runs the protos tail.
__global__ __launch_bounds__(256) void sreduce_fused(const float* __restrict__ s0,
                                                     const float* __restrict__ s1,
                                                     const float* __restrict__ s2,
                                                     const int* __restrict__ mask,
                                                     const float* __restrict__ R0p,
                                                     const float* __restrict__ R1p,
                                                     const float* __restrict__ R2p,
                                                     float* __restrict__ wsm0,
                                                     float* __restrict__ wsm1,
                                                     float* __restrict__ wsm2,
                                                     float* __restrict__ msum,
                                                     float* __restrict__ fgnum,
                                                     float* __restrict__ tot,
                                                     float* __restrict__ c0v,
                                                     float* __restrict__ c1v,
                                                     float* __restrict__ rn0v,
                                                     float* __restrict__ rn1v,
                                                     float* __restrict__ minv,
                                                     float* __restrict__ rg,
                                                     int* __restrict__ cnt) {
    int c = blockIdx.x, b = blockIdx.y, level = blockIdx.z, tid = threadIdx.x;
    int w = 64 >> level, HW = w * w, HW4 = HW >> 2, S = 8 << level;
    const float* s = (level == 0) ? s0 : ((level == 1) ? s1 : s2);
    float* wsm = (level == 0) ? wsm0 : ((level == 1) ? wsm1 : wsm2);
    const int* mb = mask + (size_t)b * 512 * 512;
    const float4* sb4 = (const float4*)(s + ((size_t)(b * 256) + c) * HW);
    bool writer = (c == 0);
    float af = 0.f, at = 0.f, am = 0.f;
    for (int i = tid; i < HW4; i += 256) {
        int n = 4 * i; int y = n / w; int x0 = n - y * w;
        const int* mrow = mb + (size_t)y * S * 512 + (size_t)x0 * S;
        float m0 = (float)mrow[0], m1 = (float)mrow[S];
        float m2 = (float)mrow[2 * S], m3 = (float)mrow[3 * S];
        float4 x = sb4[i];
        at += (x.x + x.y) + (x.z + x.w);
        af = fmaf(x.x, m0, fmaf(x.y, m1, fmaf(x.z, m2, fmaf(x.w, m3, af))));
        if (writer) {
            ((float4*)(wsm + (size_t)b * HW))[i] = make_float4(m0, m1, m2, m3);
            am += (m0 + m1) + (m2 + m3);
        }
    }
    __shared__ float redA[256], redB[256];
    redA[tid] = af; redB[tid] = at; __syncthreads();
    for (int off = 128; off > 0; off >>= 1) {
        if (tid < off) { redA[tid] += redA[tid + off]; redB[tid] += redB[tid + off]; }
        __syncthreads();
    }
    int base = (level * 8 + b) * 256;
    if (tid == 0) { fgnum[base + c] = redA[0]; tot[base + c] = redB[0]; }
    __syncthreads();
    if (writer) {   // block-uniform condition -> barriers inside are safe
        float amsum = block_reduce_sum(am, redA);
        if (tid == 0) msum[b * 3 + level] = amsum;
    }

    // elect last block of this (b,level) group to run protos
    __threadfence();
    __shared__ int done;
    if (tid == 0) done = atomicAdd(&cnt[level * 8 + b], 1);
    __syncthreads();
    if (done == 255) {
        __threadfence();   // acquire: make other blocks' fgnum/tot/msum visible
        const float* R = (level == 0) ? R0p : ((level == 1) ? R1p : R2p);
        float ms = msum[b * 3 + level];
        float denf = ms + EPSF;
        float denb = ((float)HW - ms) + EPSF;
        float fgv = fgnum[base + tid];
        float ttv = tot[base + tid];
        float pf = fgv / denf;            // proto_fg
        float pb = (ttv - fgv) / denb;    // proto_bg
        float nf = block_reduce_sum(pf * pf, redA);
        float nb_ = block_reduce_sum(pb * pb, redA);
        float C1 = pf / (sqrtf(nf) + EPSF);   // row 1 = fg
        float C0 = pb / (sqrtf(nb_) + EPSF);  // row 0 = bg
        c0v[base + tid] = C0;
        c1v[base + tid] = C1;
        float r0 = R[tid], r1 = R[256 + tid];
        float n0 = block_reduce_sum(r0 * r0, redA);
        float n1 = block_reduce_sum(r1 * r1, redA);
        float rr = block_reduce_sum(r0 * r1, redA);
        float i0 = 1.0f / (sqrtf(n0) + EPSF);
        float i1 = 1.0f / (sqrtf(n1) + EPSF);
        rn0v[base + tid] = r0 * i0;
        rn1v[base + tid] = r1 * i1;
        float a  = block_reduce_sum(C0 * C0, redA);
        float bb = block_reduce_sum(C0 * C1, redA);
        float cc = block_reduce_sum(C1 * C1, redA);
        if (tid == 0) {
            float det = a * cc - bb * bb;
            float id = 1.0f / det;
            float* M = minv + (level * 8 + b) * 4;
            M[0] = cc * id; M[1] = -bb * id; M[2] = -bb * id; M[3] = a * id;
            float* G = rg + (level * 8 + b) * 4;
            G[0] = n0 * i0 * i0;   // sum Rn0^2
            G[1] = rr * i0 * i1;   // sum Rn0*Rn1
            G[2] = n1 * i1 * i1;   // sum Rn1^2
        }
    }
}

// grid (84, 8) : x encodes (is_s, level, blk of 128 pixels); block 256
__global__ __launch_bounds__(256) void transform_kernel(const float* __restrict__ q0,
                                                        const float* __restrict__ q1,
                                                        const float* __restrict__ q2,
                                                        const float* __restrict__ s0,
                                                        const float* __restrict__ s1,
                                                        const float* __restrict__ s2,
                                                        float* __restrict__ out,
                                                        const float* __restrict__ c0v,
                                                        const float* __restrict__ c1v,
                                                        const float* __restrict__ rn0v,
                                                        const float* __restrict__ rn1v,
                                                        const float* __restrict__ minv,
                                                        const float* __restrict__ wsm0,
                                                        const float* __restrict__ wsm1,
                                                        const float* __restrict__ wsm2,
                                                        float* __restrict__ vbuf,
                                                        float* __restrict__ partials) {
    int b = blockIdx.y;
    int xb = blockIdx.x;
    int is_s = (xb >= 42);
    if (is_s) xb -= 42;
    int level, blk;
    if (xb < 32)      { level = 0; blk = xb; }
    else if (xb < 40) { level = 1; blk = xb - 32; }
    else              { level = 2; blk = xb - 40; }
    int HW = 4096 >> (2 * level);
    int HW4 = HW >> 2;
    const float* x = is_s ? ((level == 0) ? s0 : ((level == 1) ? s1 : s2))
                          : ((level == 0) ? q0 : ((level == 1) ? q1 : q2));
    const float* wsm = (level == 0) ? wsm0 : ((level == 1) ? wsm1 : wsm2);
    const int qoffs[3] = {0, 4096, 5120};
    const int soffs[3] = {5376, 9472, 10496};
    int col_off = is_s ? soffs[level] : qoffs[level];
    int n0 = blk * 128;
    int tid = threadIdx.x;

    __shared__ float sc0[256], sc1[256], srn0[256], srn1[256];
    __shared__ float st0[8][32][4], st1[8][32][4];
    __shared__ float4 su4[64];          // (u0,u1) pairs for 128 pixels
    __shared__ float pred[2][4];
    int base = (level * 8 + b) * 256;
    sc0[tid] = c0v[base + tid];
    sc1[tid] = c1v[base + tid];
    srn0[tid] = rn0v[base + tid];
    srn1[tid] = rn1v[base + tid];
    __syncthreads();

    // phase 1: partial dots, float4 loads
    const float4* xb4 = (const float4*)(x + (size_t)(b * 256) * HW);
    int cg = tid >> 5, l = tid & 31;
    size_t idx0 = (size_t)(cg * 32) * HW4 + (n0 >> 2) + l;
    float t0x = 0, t0y = 0, t0z = 0, t0w = 0;
    float t1x = 0, t1y = 0, t1z = 0, t1w = 0;
    #pragma unroll 8
    for (int i = 0; i < 32; i++) {
        int c = cg * 32 + i;
        float4 xv = xb4[idx0 + (size_t)i * HW4];
        float a = sc0[c], bq = sc1[c];
        t0x = fmaf(a, xv.x, t0x); t0y = fmaf(a, xv.y, t0y);
        t0z = fmaf(a, xv.z, t0z); t0w = fmaf(a, xv.w, t0w);
        t1x = fmaf(bq, xv.x, t1x); t1y = fmaf(bq, xv.y, t1y);
        t1z = fmaf(bq, xv.z, t1z); t1w = fmaf(bq, xv.w, t1w);
    }
    st0[cg][l][0] = t0x; st0[cg][l][1] = t0y; st0[cg][l][2] = t0z; st0[cg][l][3] = t0w;
    st1[cg][l][0] = t1x; st1[cg][l][1] = t1y; st1[cg][l][2] = t1z; st1[cg][l][3] = t1w;
    __syncthreads();

    // phase 2: per-pixel u, fully parallel over 128 threads
    if (tid < 128) {
        int p = tid;
        const float* f0 = &st0[0][p >> 2][p & 3];
        const float* f1 = &st1[0][p >> 2][p & 3];
        float a0 = 0.f, a1 = 0.f;
        #pragma unroll
        for (int g2 = 0; g2 < 8; g2++) {
            a0 += f0[g2 * 128];
            a1 += f1[g2 * 128];
        }
        const float* M = minv + (level * 8 + b) * 4;
        float u0 = M[0] * a0 + M[1] * a1;
        float u1 = M[1] * a0 + M[3] * a1;
        ((float2*)su4)[p] = make_float2(u0, u1);
        if (is_s) {
            int n = n0 + p;
            if (level == 0) {
                *(float2*)&vbuf[((size_t)b * 4096 + n) * 2] = make_float2(u0, u1);
            }
            float m = wsm[b * HW + n];
            float s0r = m * u0, s1r = m * u1, s2r = u0, s3r = u1;
            for (int off = 32; off > 0; off >>= 1) {
                s0r += __shfl_down(s0r, off, 64);
                s1r += __shfl_down(s1r, off, 64);
                s2r += __shfl_down(s2r, off, 64);
                s3r += __shfl_down(s3r, off, 64);
            }
            if ((tid & 63) == 0) {
                int wv = tid >> 6;
                pred[wv][0] = s0r; pred[wv][1] = s1r;
                pred[wv][2] = s2r; pred[wv][3] = s3r;
            }
        }
    }
    __syncthreads();
    if (is_s && tid == 0) {
        float* pp = partials + (((level * 8 + b) * 64) + blk) * 4;
        pp[0] = pred[0][0] + pred[1][0];
        pp[1] = pred[0][1] + pred[1][1];
        pp[2] = pred[0][2] + pred[1][2];
        pp[3] = pred[0][3] + pred[1][3];
    }

    // phase 3: rank-2 reconstruction, float2 stores (NTOT even -> exact float2 grid)
    int g = tid >> 6, slot = tid & 63;          // slot covers pixels 2*slot, 2*slot+1
    float4 sq = su4[slot];                      // (u0a,u1a,u0b,u1b)
    float2* ob2 = (float2*)out + ((size_t)(b * 256) + g * 64) * NTOT2
                  + ((col_off + n0) >> 1) + slot;
    #pragma unroll 8
    for (int i = 0; i < 64; i++) {
        int c = g * 64 + i;
        float r0 = srn0[c], r1 = srn1[c];
        ob2[(size_t)i * NTOT2] = make_float2(fmaf(r0, sq.x, r1 * sq.y),
                                             fmaf(r0, sq.z, r1 * sq.w));
    }
}

// grid 8 (batch), block 1024 = 16 waves; bitonic top-32 + tokens + protoT
__global__ __launch_bounds__(1024) void final_kernel(float* __restrict__ out,
                                                     const float* __restrict__ v,
                                                     const float* __restrict__ wsm0,
                                                     const float* __restrict__ msum,
                                                     const float* __restrict__ rn0v,
                                                     const float* __restrict__ rn1v,
                                                     const float* __restrict__ rg,
                                                     const float* __restrict__ partials) {
    int b = blockIdx.x, tid = threadIdx.x;
    int w = tid >> 6, lane = tid & 63;
    __shared__ float lds_s[16 * 64];
    __shared__ int   lds_i[16 * 64];
    __shared__ float2 suv[32];
    __shared__ float sA[3][4];

    float A = rg[b * 4 + 0], B = rg[b * 4 + 1], C = rg[b * 4 + 2];
    bool validmask = msum[b * 3 + 0] > 0.0f;

    // per-wave: 4 chunks of 64 pixels -> sorted-desc top-64 in registers
    float as; int ai;
    #pragma unroll
    for (int c4 = 0; c4 < 4; ++c4) {
        int n = (w * 4 + c4) * 64 + lane;
        float2 uv = *(const float2*)&v[((size_t)b * 4096 + n) * 2];
        float ss = fmaxf(A * uv.x * uv.x + 2.0f * B * uv.x * uv.y + C * uv.y * uv.y, 0.0f);
        float s = sqrtf(ss);
        float m = validmask ? wsm0[b * 4096 + n] : 1.0f;
        s = (m >= 0.5f) ? s : -INFINITY;
        int i = n;
        sort64(s, i, lane);
        if (c4 == 0) { as = s; ai = i; }
        else merge64(as, ai, s, i, lane);
    }
    lds_s[w * 64 + lane] = as;
    lds_i[w * 64 + lane] = ai;
    __syncthreads();

    // cross-wave merge tree: 16 -> 8 -> 4 -> 2 -> 1
    for (int act = 8; act >= 1; act >>= 1) {
        float ms_; int mi_;
        bool active = (w < act);
        if (active) {
            ms_ = lds_s[(2 * w) * 64 + lane];
            mi_ = lds_i[(2 * w) * 64 + lane];
            float bs_ = lds_s[(2 * w + 1) * 64 + lane];
            int   bi_ = lds_i[(2 * w + 1) * 64 + lane];
            merge64(ms_, mi_, bs_, bi_, lane);
        }
        __syncthreads();
        if (active) {
            lds_s[w * 64 + lane] = ms_;
            lds_i[w * 64 + lane] = mi_;
        }
        __syncthreads();
    }

    // list 0 = descending top-64; lanes 0..31 = top-32 in lax.top_k order
    if (tid < 32) {
        int idx = lds_i[tid];
        suv[tid] = *(const float2*)&v[((size_t)b * 4096 + idx) * 2];
    }
    __syncthreads();

    // tokens: thread t -> row c = t>>2, 4 float2 slots; contiguous 128 B per row
    int c = tid >> 2, qd = tid & 3;
    float r0 = rn0v[b * 256 + c], r1 = rn1v[b * 256 + c];
    float2* o2 = (float2*)out + ((size_t)(b * 256) + c) * NTOT2 + 5379 + qd * 4;
    #pragma unroll
    for (int t = 0; t < 4; ++t) {
        float2 uv0 = suv[qd * 8 + 2 * t];
        float2 uv1 = suv[qd * 8 + 2 * t + 1];
        o2[t] = make_float2(fmaf(r0, uv0.x, r1 * uv0.y),
                            fmaf(r0, uv1.x, r1 * uv1.y));
    }

    // protoT: transformed fg/bg prototypes for 3 levels
    if (tid < 3) {
        int lv = tid;
        const int HWl[3] = {4096, 1024, 256};
        const int nbl[3] = {32, 8, 2};
        const float* pp = partials + ((size_t)(lv * 8 + b) * 64) * 4;
        float t0 = 0, t1 = 0, t2 = 0, t3 = 0;
        for (int i = 0; i < nbl[lv]; i++) {
            t0 += pp[i * 4 + 0]; t1 += pp[i * 4 + 1];
            t2 += pp[i * 4 + 2]; t3 += pp[i * 4 + 3];
        }
        float ms = msum[b * 3 + lv];
        float denf = ms + EPSF;
        float denb = ((float)HWl[lv] - ms) + EPSF;
        sA[lv][0] = t0 / denf;          // fg avg of u0
        sA[lv][1] = t1 / denf;          // fg avg of u1
        sA[lv][2] = (t2 - t0) / denb;   // bg avg of u0
        sA[lv][3] = (t3 - t1) / denb;   // bg avg of u1
    }
    __syncthreads();
    if (tid < 768) {
        int lv = tid >> 8, cc = tid & 255;
        int base = (lv * 8 + b) * 256;
        float rr0 = rn0v[base + cc], rr1 = rn1v[base + cc];
        size_t row = ((size_t)(b * 256) + cc) * NTOT;
        out[row + 10752 + lv] = fmaf(rr0, sA[lv][0], rr1 * sA[lv][1]);
        out[row + 10755 + lv] = fmaf(rr0, sA[lv][2], rr1 * sA[lv][3]);
    }
}

extern "C" void kernel_launch(void* const* d_in, const int* in_sizes, int n_in,
                              void* d_out, int out_size, void* d_ws, size_t ws_size,
                              hipStream_t stream) {
    // dict order: q1,s1,r1, q2,s2,r2, q3,s3,r3, support_mask, k
    const float* q0 = (const float*)d_in[0];
    const float* s0 = (const float*)d_in[1];
    const float* r0 = (const float*)d_in[2];
    const float* q1 = (const float*)d_in[3];
    const float* s1 = (const float*)d_in[4];
    const float* r1 = (const float*)d_in[5];
    const float* q2 = (const float*)d_in[6];
    const float* s2 = (const float*)d_in[7];
    const float* r2 = (const float*)d_in[8];
    const int* mask = (const int*)d_in[9];
    float* out = (float*)d_out;
    float* W = (float*)d_ws;

    float* wsm0 = W;              // 8*4096      = 32768
    float* wsm1 = W + 32768;      // 8*1024      =  8192
    float* wsm2 = W + 40960;      // 8*256       =  2048
    float* msum = W + 43008;      // 8*3 (pad)   ->   32
    float* fgnum = W + 43040;     // 3*8*256     =  6144
    float* tot  = W + 49184;      // 6144
    float* c0v  = W + 55328;      // 6144
    float* c1v  = W + 61472;      // 6144
    float* rn0v = W + 67616;      // 6144
    float* rn1v = W + 73760;      // 6144
    float* minv = W + 79904;      // 3*8*4 = 96
    float* rg   = W + 80000;      // 3*8*4 = 96 (pad 128)
    float* vbuf = W + 80128;      // 8*4096*2 = 65536
    float* part = W + 145664;     // 3*8*64*4 = 6144
    int*   cnt  = (int*)(W + 151808);   // 24 ints

    hipMemsetAsync(cnt, 0, 24 * sizeof(int), stream);

    sreduce_fused<<<dim3(256, 8, 3), 256, 0, stream>>>(s0, s1, s2, mask, r0, r1, r2,
                                                       wsm0, wsm1, wsm2, msum,
                                                       fgnum, tot, c0v, c1v,
                                                       rn0v, rn1v, minv, rg, cnt);

    transform_kernel<<<dim3(84, 8), 256, 0, stream>>>(q0, q1, q2, s0, s1, s2, out,
                                                      c0v, c1v, rn0v, rn1v, minv,
                                                      wsm0, wsm1, wsm2, vbuf, part);

    final_kernel<<<8, 1024, 0, stream>>>(out, vbuf, wsm0, msum, rn0v, rn1v, rg, part);
}

// Round 6
// 77.361 us; speedup vs baseline: 7.3788x; 7.3788x over previous
//
#include <hip/hip_runtime.h>
#include <math.h>

#define NTOT 10790
#define NTOT2 5395
#define EPSF 1e-6f

__device__ __forceinline__ float block_reduce_sum(float v, float* red) {
    int tid = threadIdx.x;
    red[tid] = v; __syncthreads();
    for (int off = 128; off > 0; off >>= 1) {
        if (tid < off) red[tid] += red[tid + off];
        __syncthreads();
    }
    float r = red[0];
    __syncthreads();
    return r;
}

// strict total order: score desc, idx asc (idx unique -> never equal)
__device__ __forceinline__ bool kvGreater(float as, int ai, float bs, int bi) {
    return (as > bs) || (as == bs && ai < bi);
}

// bitonic sort of 64 lanes' (s,i), descending, register-only
__device__ __forceinline__ void sort64(float& s, int& i, int lane) {
    #pragma unroll
    for (int k = 2; k <= 64; k <<= 1) {
        #pragma unroll
        for (int j = k >> 1; j > 0; j >>= 1) {
            float os = __shfl_xor(s, j, 64);
            int   oi = __shfl_xor(i, j, 64);
            bool lower = (lane & j) == 0;
            bool blockDesc = (lane & k) == 0;
            bool keepG = (blockDesc == lower);
            bool og = kvGreater(os, oi, s, i);
            if (og == keepG) { s = os; i = oi; }
        }
    }
}

// merge two descending sorted-64 lists (a, b) -> a = descending top-64 of union
__device__ __forceinline__ void merge64(float& as, int& ai, float bs, int bi, int lane) {
    float rbs = __shfl(bs, 63 - lane, 64);
    int   rbi = __shfl(bi, 63 - lane, 64);
    if (!kvGreater(as, ai, rbs, rbi)) { as = rbs; ai = rbi; }
    #pragma unroll
    for (int j = 32; j > 0; j >>= 1) {
        float os = __shfl_xor(as, j, 64);
        int   oi = __shfl_xor(ai, j, 64);
        bool lower = (lane & j) == 0;
        bool og = kvGreater(os, oi, as, ai);
        if (og == lower) { as = os; ai = oi; }
    }
}

// grid (3 levels, 8 batch), block 256
__global__ __launch_bounds__(256) void mask_kernel(const int* __restrict__ mask,
                                                   float* __restrict__ wsm0,
                                                   float* __restrict__ wsm1,
                                                   float* __restrict__ wsm2,
                                                   float* __restrict__ msum) {
    int level = blockIdx.x, b = blockIdx.y, tid = threadIdx.x;
    int h = 64 >> level, w = h, S = 8 << level, HW = h * w;
    float* wsm = (level == 0) ? wsm0 : ((level == 1) ? wsm1 : wsm2);
    const int* mb = mask + (size_t)b * 512 * 512;
    float acc = 0.f;
    for (int n = tid; n < HW; n += 256) {
        int y = n / w, x = n - y * w;
        float mv = (float)mb[y * S * 512 + x * S];
        wsm[b * HW + n] = mv;
        acc += mv;
    }
    __shared__ float red[256];
    float s = block_reduce_sum(acc, red);
    if (tid == 0) msum[b * 3 + level] = s;
}

// grid (256 channels, 8 batch, 3 levels), block 256 over pixels; float4 streams
__global__ __launch_bounds__(256) void sreduce_kernel(const float* __restrict__ s0,
                                                      const float* __restrict__ s1,
                                                      const float* __restrict__ s2,
                                                      const float* __restrict__ wsm0,
                                                      const float* __restrict__ wsm1,
                                                      const float* __restrict__ wsm2,
                                                      float* __restrict__ fgnum,
                                                      float* __restrict__ tot) {
    int c = blockIdx.x, b = blockIdx.y, level = blockIdx.z, tid = threadIdx.x;
    int HW = 4096 >> (2 * level);
    int HW4 = HW >> 2;
    const float* s = (level == 0) ? s0 : ((level == 1) ? s1 : s2);
    const float* wsm = (level == 0) ? wsm0 : ((level == 1) ? wsm1 : wsm2);
    const float4* sb4 = (const float4*)(s + ((size_t)(b * 256) + c) * HW);
    const float4* mb4 = (const float4*)(wsm + (size_t)b * HW);
    float af = 0.f, at = 0.f;
    for (int i = tid; i < HW4; i += 256) {
        float4 x = sb4[i];
        float4 m = mb4[i];
        at += (x.x + x.y) + (x.z + x.w);
        af = fmaf(x.x, m.x, fmaf(x.y, m.y, fmaf(x.z, m.z, fmaf(x.w, m.w, af))));
    }
    __shared__ float redA[256], redB[256];
    redA[tid] = af; redB[tid] = at; __syncthreads();
    for (int off = 128; off > 0; off >>= 1) {
        if (tid < off) { redA[tid] += redA[tid + off]; redB[tid] += redB[tid + off]; }
        __syncthreads();
    }
    if (tid == 0) {
        int base = (level * 8 + b) * 256 + c;
        fgnum[base] = redA[0];
        tot[base]   = redB[0];
    }
}

// grid (8 batch, 3 levels), block 256 (channels)
__global__ __launch_bounds__(256) void protos_kernel(const float* __restrict__ R0p,
                                                     const float* __restrict__ R1p,
                                                     const float* __restrict__ R2p,
                                                     const float* __restrict__ fgnum,
                                                     const float* __restrict__ tot,
                                                     const float* __restrict__ msum,
                                                     float* __restrict__ c0v,
                                                     float* __restrict__ c1v,
                                                     float* __restrict__ rn0v,
                                                     float* __restrict__ rn1v,
                                                     float* __restrict__ minv,
                                                     float* __restrict__ rg) {
    int b = blockIdx.x, level = blockIdx.y, c = threadIdx.x;
    int HW = 4096 >> (2 * level);
    const float* R = (level == 0) ? R0p : ((level == 1) ? R1p : R2p);
    __shared__ float red[256];
    int base = (level * 8 + b) * 256;
    float ms = msum[b * 3 + level];
    float denf = ms + EPSF;
    float denb = ((float)HW - ms) + EPSF;
    float fg = fgnum[base + c];
    float tt = tot[base + c];
    float pf = fg / denf;            // proto_fg
    float pb = (tt - fg) / denb;     // proto_bg
    float nf = block_reduce_sum(pf * pf, red);
    float nb = block_reduce_sum(pb * pb, red);
    float C1 = pf / (sqrtf(nf) + EPSF);   // row 1 = fg
    float C0 = pb / (sqrtf(nb) + EPSF);   // row 0 = bg
    c0v[base + c] = C0;
    c1v[base + c] = C1;
    float r0 = R[c], r1 = R[256 + c];
    float n0 = block_reduce_sum(r0 * r0, red);
    float n1 = block_reduce_sum(r1 * r1, red);
    float rr = block_reduce_sum(r0 * r1, red);
    float i0 = 1.0f / (sqrtf(n0) + EPSF);
    float i1 = 1.0f / (sqrtf(n1) + EPSF);
    rn0v[base + c] = r0 * i0;
    rn1v[base + c] = r1 * i1;
    float a  = block_reduce_sum(C0 * C0, red);
    float bb = block_reduce_sum(C0 * C1, red);
    float cc = block_reduce_sum(C1 * C1, red);
    if (c == 0) {
        float det = a * cc - bb * bb;
        float id = 1.0f / det;
        float* M = minv + (level * 8 + b) * 4;
        M[0] = cc * id; M[1] = -bb * id; M[2] = -bb * id; M[3] = a * id;
        float* G = rg + (level * 8 + b) * 4;
        G[0] = n0 * i0 * i0;   // sum Rn0^2
        G[1] = rr * i0 * i1;   // sum Rn0*Rn1
        G[2] = n1 * i1 * i1;   // sum Rn1^2
    }
}

// grid (84, 8) : x encodes (is_s, level, blk of 128 pixels); block 256
__global__ __launch_bounds__(256) void transform_kernel(const float* __restrict__ q0,
                                                        const float* __restrict__ q1,
                                                        const float* __restrict__ q2,
                                                        const float* __restrict__ s0,
                                                        const float* __restrict__ s1,
                                                        const float* __restrict__ s2,
                                                        float* __restrict__ out,
                                                        const float* __restrict__ c0v,
                                                        const float* __restrict__ c1v,
                                                        const float* __restrict__ rn0v,
                                                        const float* __restrict__ rn1v,
                                                        const float* __restrict__ minv,
                                                        const float* __restrict__ wsm0,
                                                        const float* __restrict__ wsm1,
                                                        const float* __restrict__ wsm2,
                                                        float* __restrict__ vbuf,
                                                        float* __restrict__ partials) {
    int b = blockIdx.y;
    int xb = blockIdx.x;
    int is_s = (xb >= 42);
    if (is_s) xb -= 42;
    int level, blk;
    if (xb < 32)      { level = 0; blk = xb; }
    else if (xb < 40) { level = 1; blk = xb - 32; }
    else              { level = 2; blk = xb - 40; }
    int HW = 4096 >> (2 * level);
    int HW4 = HW >> 2;
    const float* x = is_s ? ((level == 0) ? s0 : ((level == 1) ? s1 : s2))
                          : ((level == 0) ? q0 : ((level == 1) ? q1 : q2));
    const float* wsm = (level == 0) ? wsm0 : ((level == 1) ? wsm1 : wsm2);
    const int qoffs[3] = {0, 4096, 5120};
    const int soffs[3] = {5376, 9472, 10496};
    int col_off = is_s ? soffs[level] : qoffs[level];
    int n0 = blk * 128;
    int tid = threadIdx.x;

    __shared__ float sc0[256], sc1[256], srn0[256], srn1[256];
    __shared__ float st0[8][32][4], st1[8][32][4];
    __shared__ float4 su4[64];          // (u0,u1) pairs for 128 pixels
    __shared__ float pred[2][4];
    int base = (level * 8 + b) * 256;
    sc0[tid] = c0v[base + tid];
    sc1[tid] = c1v[base + tid];
    srn0[tid] = rn0v[base + tid];
    srn1[tid] = rn1v[base + tid];
    __syncthreads();

    // phase 1: partial dots, float4 loads
    const float4* xb4 = (const float4*)(x + (size_t)(b * 256) * HW);
    int cg = tid >> 5, l = tid & 31;
    size_t idx0 = (size_t)(cg * 32) * HW4 + (n0 >> 2) + l;
    float t0x = 0, t0y = 0, t0z = 0, t0w = 0;
    float t1x = 0, t1y = 0, t1z = 0, t1w = 0;
    #pragma unroll 8
    for (int i = 0; i < 32; i++) {
        int c = cg * 32 + i;
        float4 xv = xb4[idx0 + (size_t)i * HW4];
        float a = sc0[c], bq = sc1[c];
        t0x = fmaf(a, xv.x, t0x); t0y = fmaf(a, xv.y, t0y);
        t0z = fmaf(a, xv.z, t0z); t0w = fmaf(a, xv.w, t0w);
        t1x = fmaf(bq, xv.x, t1x); t1y = fmaf(bq, xv.y, t1y);
        t1z = fmaf(bq, xv.z, t1z); t1w = fmaf(bq, xv.w, t1w);
    }
    st0[cg][l][0] = t0x; st0[cg][l][1] = t0y; st0[cg][l][2] = t0z; st0[cg][l][3] = t0w;
    st1[cg][l][0] = t1x; st1[cg][l][1] = t1y; st1[cg][l][2] = t1z; st1[cg][l][3] = t1w;
    __syncthreads();

    // phase 2: per-pixel u, fully parallel over 128 threads
    if (tid < 128) {
        int p = tid;
        const float* f0 = &st0[0][p >> 2][p & 3];
        const float* f1 = &st1[0][p >> 2][p & 3];
        float a0 = 0.f, a1 = 0.f;
        #pragma unroll
        for (int g2 = 0; g2 < 8; g2++) {
            a0 += f0[g2 * 128];
            a1 += f1[g2 * 128];
        }
        const float* M = minv + (level * 8 + b) * 4;
        float u0 = M[0] * a0 + M[1] * a1;
        float u1 = M[1] * a0 + M[3] * a1;
        ((float2*)su4)[p] = make_float2(u0, u1);
        if (is_s) {
            int n = n0 + p;
            if (level == 0) {
                *(float2*)&vbuf[((size_t)b * 4096 + n) * 2] = make_float2(u0, u1);
            }
            float m = wsm[b * HW + n];
            float s0r = m * u0, s1r = m * u1, s2r = u0, s3r = u1;
            for (int off = 32; off > 0; off >>= 1) {
                s0r += __shfl_down(s0r, off, 64);
                s1r += __shfl_down(s1r, off, 64);
                s2r += __shfl_down(s2r, off, 64);
                s3r += __shfl_down(s3r, off, 64);
            }
            if ((tid & 63) == 0) {
                int wv = tid >> 6;
                pred[wv][0] = s0r; pred[wv][1] = s1r;
                pred[wv][2] = s2r; pred[wv][3] = s3r;
            }
        }
    }
    __syncthreads();
    if (is_s && tid == 0) {
        float* pp = partials + (((level * 8 + b) * 64) + blk) * 4;
        pp[0] = pred[0][0] + pred[1][0];
        pp[1] = pred[0][1] + pred[1][1];
        pp[2] = pred[0][2] + pred[1][2];
        pp[3] = pred[0][3] + pred[1][3];
    }

    // phase 3: rank-2 reconstruction, float2 stores (NTOT even -> exact float2 grid)
    int g = tid >> 6, slot = tid & 63;          // slot covers pixels 2*slot, 2*slot+1
    float4 sq = su4[slot];                      // (u0a,u1a,u0b,u1b)
    float2* ob2 = (float2*)out + ((size_t)(b * 256) + g * 64) * NTOT2
                  + ((col_off + n0) >> 1) + slot;
    #pragma unroll 8
    for (int i = 0; i < 64; i++) {
        int c = g * 64 + i;
        float r0 = srn0[c], r1 = srn1[c];
        ob2[(size_t)i * NTOT2] = make_float2(fmaf(r0, sq.x, r1 * sq.y),
                                             fmaf(r0, sq.z, r1 * sq.w));
    }
}

// grid 8 (batch), block 1024 = 16 waves; bitonic top-32 + tokens + protoT
__global__ __launch_bounds__(1024) void final_kernel(float* __restrict__ out,
                                                     const float* __restrict__ v,
                                                     const float* __restrict__ wsm0,
                                                     const float* __restrict__ msum,
                                                     const float* __restrict__ rn0v,
                                                     const float* __restrict__ rn1v,
                                                     const float* __restrict__ rg,
                                                     const float* __restrict__ partials) {
    int b = blockIdx.x, tid = threadIdx.x;
    int w = tid >> 6, lane = tid & 63;
    __shared__ float lds_s[16 * 64];
    __shared__ int   lds_i[16 * 64];
    __shared__ float2 suv[32];
    __shared__ float sA[3][4];

    float A = rg[b * 4 + 0], B = rg[b * 4 + 1], C = rg[b * 4 + 2];
    bool validmask = msum[b * 3 + 0] > 0.0f;

    // per-wave: 4 chunks of 64 pixels -> sorted-desc top-64 in registers
    float as; int ai;
    #pragma unroll
    for (int c4 = 0; c4 < 4; ++c4) {
        int n = (w * 4 + c4) * 64 + lane;
        float2 uv = *(const float2*)&v[((size_t)b * 4096 + n) * 2];
        float ss = fmaxf(A * uv.x * uv.x + 2.0f * B * uv.x * uv.y + C * uv.y * uv.y, 0.0f);
        float s = sqrtf(ss);
        float m = validmask ? wsm0[b * 4096 + n] : 1.0f;
        s = (m >= 0.5f) ? s : -INFINITY;
        int i = n;
        sort64(s, i, lane);
        if (c4 == 0) { as = s; ai = i; }
        else merge64(as, ai, s, i, lane);
    }
    lds_s[w * 64 + lane] = as;
    lds_i[w * 64 + lane] = ai;
    __syncthreads();

    // cross-wave merge tree: 16 -> 8 -> 4 -> 2 -> 1
    for (int act = 8; act >= 1; act >>= 1) {
        float ms_; int mi_;
        bool active = (w < act);
        if (active) {
            ms_ = lds_s[(2 * w) * 64 + lane];
            mi_ = lds_i[(2 * w) * 64 + lane];
            float bs_ = lds_s[(2 * w + 1) * 64 + lane];
            int   bi_ = lds_i[(2 * w + 1) * 64 + lane];
            merge64(ms_, mi_, bs_, bi_, lane);
        }
        __syncthreads();
        if (active) {
            lds_s[w * 64 + lane] = ms_;
            lds_i[w * 64 + lane] = mi_;
        }
        __syncthreads();
    }

    // list 0 = descending top-64; lanes 0..31 = top-32 in lax.top_k order
    if (tid < 32) {
        int idx = lds_i[tid];
        suv[tid] = *(const float2*)&v[((size_t)b * 4096 + idx) * 2];
    }
    __syncthreads();

    // tokens: thread t -> row c = t>>2, 4 float2 slots; contiguous 128 B per row
    int c = tid >> 2, qd = tid & 3;
    float r0 = rn0v[b * 256 + c], r1 = rn1v[b * 256 + c];
    float2* o2 = (float2*)out + ((size_t)(b * 256) + c) * NTOT2 + 5379 + qd * 4;
    #pragma unroll
    for (int t = 0; t < 4; ++t) {
        float2 uv0 = suv[qd * 8 + 2 * t];
        float2 uv1 = suv[qd * 8 + 2 * t + 1];
        o2[t] = make_float2(fmaf(r0, uv0.x, r1 * uv0.y),
                            fmaf(r0, uv1.x, r1 * uv1.y));
    }

    // protoT: transformed fg/bg prototypes for 3 levels
    if (tid < 3) {
        int lv = tid;
        const int HWl[3] = {4096, 1024, 256};
        const int nbl[3] = {32, 8, 2};
        const float* pp = partials + ((size_t)(lv * 8 + b) * 64) * 4;
        float t0 = 0, t1 = 0, t2 = 0, t3 = 0;
        for (int i = 0; i < nbl[lv]; i++) {
            t0 += pp[i * 4 + 0]; t1 += pp[i * 4 + 1];
            t2 += pp[i * 4 + 2]; t3 += pp[i * 4 + 3];
        }
        float ms = msum[b * 3 + lv];
        float denf = ms + EPSF;
        float denb = ((float)HWl[lv] - ms) + EPSF;
        sA[lv][0] = t0 / denf;          // fg avg of u0
        sA[lv][1] = t1 / denf;          // fg avg of u1
        sA[lv][2] = (t2 - t0) / denb;   // bg avg of u0
        sA[lv][3] = (t3 - t1) / denb;   // bg avg of u1
    }
    __syncthreads();
    if (tid < 768) {
        int lv = tid >> 8, cc = tid & 255;
        int base = (lv * 8 + b) * 256;
        float rr0 = rn0v[base + cc], rr1 = rn1v[base + cc];
        size_t row = ((size_t)(b * 256) + cc) * NTOT;
        out[row + 10752 + lv] = fmaf(rr0, sA[lv][0], rr1 * sA[lv][1]);
        out[row + 10755 + lv] = fmaf(rr0, sA[lv][2], rr1 * sA[lv][3]);
    }
}

extern "C" void kernel_launch(void* const* d_in, const int* in_sizes, int n_in,
                              void* d_out, int out_size, void* d_ws, size_t ws_size,
                              hipStream_t stream) {
    // dict order: q1,s1,r1, q2,s2,r2, q3,s3,r3, support_mask, k
    const float* q0 = (const float*)d_in[0];
    const float* s0 = (const float*)d_in[1];
    const float* r0 = (const float*)d_in[2];
    const float* q1 = (const float*)d_in[3];
    const float* s1 = (const float*)d_in[4];
    const float* r1 = (const float*)d_in[5];
    const float* q2 = (const float*)d_in[6];
    const float* s2 = (const float*)d_in[7];
    const float* r2 = (const float*)d_in[8];
    const int* mask = (const int*)d_in[9];
    float* out = (float*)d_out;
    float* W = (float*)d_ws;

    float* wsm0 = W;              // 8*4096      = 32768
    float* wsm1 = W + 32768;      // 8*1024      =  8192
    float* wsm2 = W + 40960;      // 8*256       =  2048
    float* msum = W + 43008;      // 8*3 (pad)   ->   32
    float* fgnum = W + 43040;     // 3*8*256     =  6144
    float* tot  = W + 49184;      // 6144
    float* c0v  = W + 55328;      // 6144
    float* c1v  = W + 61472;      // 6144
    float* rn0v = W + 67616;      // 6144
    float* rn1v = W + 73760;      // 6144
    float* minv = W + 79904;      // 3*8*4 = 96
    float* rg   = W + 80000;      // 3*8*4 = 96 (pad 128)
    float* vbuf = W + 80128;      // 8*4096*2 = 65536
    float* part = W + 145664;     // 3*8*64*4 = 6144

    mask_kernel<<<dim3(3, 8), 256, 0, stream>>>(mask, wsm0, wsm1, wsm2, msum);

    sreduce_kernel<<<dim3(256, 8, 3), 256, 0, stream>>>(s0, s1, s2, wsm0, wsm1, wsm2,
                                                        fgnum, tot);

    protos_kernel<<<dim3(8, 3), 256, 0, stream>>>(r0, r1, r2, fgnum, tot, msum,
                                                  c0v, c1v, rn0v, rn1v, minv, rg);

    transform_kernel<<<dim3(84, 8), 256, 0, stream>>>(q0, q1, q2, s0, s1, s2, out,
                                                      c0v, c1v, rn0v, rn1v, minv,
                                                      wsm0, wsm1, wsm2, vbuf, part);

    final_kernel<<<8, 1024, 0, stream>>>(out, vbuf, wsm0, msum, rn0v, rn1v, rg, part);
}